// Round 6
// baseline (822.581 us; speedup 1.0000x reference)
//
#include <hip/hip_runtime.h>

// CrossScaleAttention on MI355X — round 6.
// R5 post-mortem: fused skeleton carries ~470 µs of fixed serialization
// (barrier joins + staging latency inside the barrier window + V from L3 due
// to sample interleave). R3's split kscoreP measured 834 TF; its kpv failed
// only on grid size (144 blocks). R6: nb=2 split pipeline:
//   kscoreP: fp16 score (Q frags in regs, Ks LDS only) -> P bf16 + l atomics
//   kpv:     BARRIER-FREE zero-LDS GEMM, P/V frags straight from global
//            (XCD-sample affinity), Z f32 OVERLAYS P in-place (block-private)
//   kgather: parity-stencil overlap-add (stride adapted to overlay layout)
// Workspace nb=2 = 101,320,704 B <= 105,625,600 proven available.
//
// Layout:
//   xf16 : [4][98][98][32] fp16 match_input, zero halo        2,458,624
//   rkl  : [4][50][50][32] fp16 ref, zero halo                  640,000
//   ef32 : [4][50][50][64] f32 embed_w, zero halo             2,560,000
//   vtp  : [4][576][2304] bf16 V^T (n=tap*64+c, l=ly*48+lx)  10,616,832
//   invn : [4][2304] f32 10/max(norm,1e-4)                       36,864
//   lsum : [nb][9216] f32                                     nb*36,864
//   P    : [nb][9216][2304] bf16; after kpv, row q bytes 0..2303 hold
//          Z[q][576] f32 (block-private overlay)          nb*42,467,328

typedef unsigned short u16;
typedef __attribute__((ext_vector_type(8))) short short8;      // 8 bf16
typedef __attribute__((ext_vector_type(8))) _Float16 half8;    // 8 fp16
typedef __attribute__((ext_vector_type(4))) float f32x4;

__device__ __forceinline__ u16 f2bf(float f) {
    unsigned u = __float_as_uint(f);
    unsigned r = (u + 0x7FFFu + ((u >> 16) & 1u)) >> 16;   // RNE
    return (u16)r;
}
__device__ __forceinline__ float bf2f(u16 h) {
    return __uint_as_float(((unsigned)h) << 16);
}
__device__ __forceinline__ u16 f2h(float f) {
    _Float16 h = (_Float16)f;           // v_cvt_f16_f32 (RNE)
    u16 u; __builtin_memcpy(&u, &h, 2); return u;
}
__device__ __forceinline__ float h2f(u16 u) {
    _Float16 h; __builtin_memcpy(&h, &u, 2); return (float)h;
}

// ---------------------------------------------------------------- zero fill
__global__ void kzero(float4* p, long n) {
    long i = (long)blockIdx.x * blockDim.x + threadIdx.x;
    long st = (long)gridDim.x * blockDim.x;
    float4 z; z.x = 0.f; z.y = 0.f; z.z = 0.f; z.w = 0.f;
    for (; i < n; i += st) p[i] = z;
}

// ------------------------------------------------- match_input -> xf16
__global__ void kmatch(const float* __restrict__ input, const float* __restrict__ w1,
                       const float* __restrict__ b1, const float* __restrict__ a1,
                       u16* __restrict__ xf16) {
    __shared__ float xl[64 * 96];
    __shared__ float wl[32 * 65];
    int b = blockIdx.x / 96, y = blockIdx.x % 96;
    int tid = threadIdx.x;
    for (int i = tid; i < 64 * 96; i += 256) {
        int ci = i / 96, xx = i % 96;
        xl[i] = input[(((b * 64 + ci) * 96) + y) * 96 + xx];
    }
    for (int i = tid; i < 2048; i += 256) wl[(i >> 6) * 65 + (i & 63)] = w1[i];
    __syncthreads();
    float aa = a1[0];
    for (int o = tid; o < 96 * 32; o += 256) {
        int xx = o >> 5, c = o & 31;
        float acc = b1[c];
        #pragma unroll
        for (int ci = 0; ci < 64; ci++) acc = fmaf(xl[ci * 96 + xx], wl[c * 65 + ci], acc);
        float v = acc >= 0.f ? acc : aa * acc;
        xf16[((b * 98 + y + 1) * 98 + (xx + 1)) * 32 + c] = f2h(v);
    }
}

// --------------------- small -> ef32 (embed, f32) + rkl fp16 (ref)
__global__ void ksmall(const float* __restrict__ small, const float* __restrict__ wasm,
                       const float* __restrict__ basm, const float* __restrict__ aasm,
                       const float* __restrict__ wm2, const float* __restrict__ bm2,
                       const float* __restrict__ am2,
                       float* __restrict__ ef32, u16* __restrict__ rkl) {
    __shared__ float sl[64 * 48];
    __shared__ float wa[64 * 65];
    __shared__ float wm[32 * 65];
    int b = blockIdx.x / 48, y = blockIdx.x % 48;
    int tid = threadIdx.x;
    for (int i = tid; i < 64 * 48; i += 256) {
        int ci = i / 48, xx = i % 48;
        sl[i] = small[(((b * 64 + ci) * 48) + y) * 48 + xx];
    }
    for (int i = tid; i < 4096; i += 256) wa[(i >> 6) * 65 + (i & 63)] = wasm[i];
    for (int i = tid; i < 2048; i += 256) wm[(i >> 6) * 65 + (i & 63)] = wm2[i];
    __syncthreads();
    float ae = aasm[0], ar = am2[0];
    for (int o = tid; o < 48 * 64; o += 256) {            // embed_w
        int xx = o >> 6, c = o & 63;
        float acc = basm[c];
        #pragma unroll
        for (int ci = 0; ci < 64; ci++) acc = fmaf(sl[ci * 48 + xx], wa[c * 65 + ci], acc);
        float v = acc >= 0.f ? acc : ae * acc;
        ef32[((b * 50 + y + 1) * 50 + (xx + 1)) * 64 + c] = v;
    }
    for (int o = tid; o < 48 * 32; o += 256) {            // ref -> rkl fp16
        int xx = o >> 5, c = o & 31;
        float acc = bm2[c];
        #pragma unroll
        for (int ci = 0; ci < 64; ci++) acc = fmaf(sl[ci * 48 + xx], wm[c * 65 + ci], acc);
        float v = acc >= 0.f ? acc : ar * acc;
        rkl[((b * 50 + y + 1) * 50 + (xx + 1)) * 32 + c] = f2h(v);
    }
}

// ------------------------------------------------------------ invnorm per key
__global__ void kinvnorm(const u16* __restrict__ rkl, float* __restrict__ invn) {
    int idx = blockIdx.x * 256 + threadIdx.x;   // 9216 exact
    int b = idx / 2304, l = idx % 2304;
    int ly = l / 48, lx = l % 48;
    float s = 0.f;
    for (int ty = 0; ty < 3; ty++)
        for (int tx = 0; tx < 3; tx++) {
            int base = ((b * 50 + ly + ty) * 50 + (lx + tx)) * 32;
            #pragma unroll
            for (int c = 0; c < 32; c++) {
                float v = h2f(rkl[base + c]);
                s = fmaf(v, v, s);
            }
        }
    invn[idx] = 10.f / fmaxf(sqrtf(s), 1e-4f);   // SCALE folded in
}

// ------------------------------------------------------------- pack V^T bf16
__global__ void kvtp(const float* __restrict__ ef32, u16* __restrict__ vtp) {
    int bi = blockIdx.x;
    int b = bi / 576, n = bi % 576;
    int t = n >> 6, c = n & 63;
    int ty = t / 3, tx = t % 3;
    const float* eb = ef32 + (size_t)b * 50 * 50 * 64 + c;
    u16* vo = vtp + (size_t)(b * 576 + n) * 2304;
    for (int l = threadIdx.x; l < 2304; l += 256) {
        int ly = l / 48, lx = l - ly * 48;
        vo[l] = f2bf(eb[((ly + ty) * 50 + (lx + tx)) * 64]);
    }
}

// ------------------------------------------------------------- score -> P + l
// grid = nb*576 (XCD-affine for nb=2). Block 256 = 4 waves (mh = M-pair,
// nh = key row). 6 iters x 96 keys. Q frags in registers (15 half8, loaded
// once from global); Ks 4 halo rows fp16 in LDS (12.8 KB). fp16 single-pass
// score (R5-validated). p = exp(s*invs) -> P bf16 global; l in regs,
// one atomicAdd per row per wave at the end (R3-proven).
__launch_bounds__(256, 3)
__global__ void kscoreP(const u16* __restrict__ xf16, const u16* __restrict__ rkl,
                        const float* __restrict__ invn, u16* __restrict__ P,
                        float* __restrict__ lsum, int b0, int nb) {
    __shared__ u16 Ks[4 * 50 * 32];   // 12800 B

    int tid = threadIdx.x;
    int w = tid >> 6, lane = tid & 63, l15 = lane & 15, quad = lane >> 4;
    int mh = w & 1, nh = w >> 1;
    int bi = blockIdx.x, brel, idx;
    if (nb == 2) { brel = (bi & 7) >> 2; idx = (bi >> 3) * 4 + (bi & 3); }
    else         { brel = 0; idx = bi; }
    int b = b0 + brel;
    int t = idx % 144, g = idx / 144;
    int px0 = (t % 6) * 16, py0 = (t / 6) * 4;

    const u16* xb = xf16 + (size_t)b * 98 * 98 * 32;
    const u16* rb = rkl + (size_t)b * 80000;
    const float* invb = invn + b * 2304;
    u16* Pb = P + (size_t)brel * 9216 * 2304;
    float* lb = lsum + brel * 9216;

    // Q fragments in registers: halo rows py0+2mh+u (u=0..4), cols px0+l15+tx
    half8 qf[5][3];
    #pragma unroll
    for (int u = 0; u < 5; ++u)
        #pragma unroll
        for (int tx = 0; tx < 3; ++tx)
            qf[u][tx] = *(const half8*)(xb + ((py0 + 2 * mh + u) * 98 + (px0 + l15 + tx)) * 32 + quad * 8);

    float lacc[2][4] = {{0.f, 0.f, 0.f, 0.f}, {0.f, 0.f, 0.f, 0.f}};

    for (int it = 0; it < 6; ++it) {
        int ly0 = g * 12 + it * 2;
        __syncthreads();   // previous iter done reading Ks
        for (int id = tid; id < 800; id += 256)
            *(short8*)&Ks[id * 8] = *(const short8*)(rb + ly0 * 1600 + id * 8);
        __syncthreads();

        f32x4 sf[6];
        #pragma unroll
        for (int i = 0; i < 6; i++) sf[i] = (f32x4)0.f;
        #pragma unroll
        for (int ty = 0; ty < 3; ++ty)
            #pragma unroll
            for (int tx = 0; tx < 3; ++tx)
                #pragma unroll
                for (int lxo = 0; lxo < 3; ++lxo) {
                    half8 bb = *(const half8*)&Ks[(nh + ty) * 1600 + (lxo * 16 + l15 + tx) * 32 + quad * 8];
                    #pragma unroll
                    for (int mt = 0; mt < 2; ++mt)
                        sf[mt * 3 + lxo] = __builtin_amdgcn_mfma_f32_16x16x32_f16(
                            qf[mt + ty][tx], bb, sf[mt * 3 + lxo], 0, 0, 0);
                }

        float invs[3];
        #pragma unroll
        for (int lxo = 0; lxo < 3; ++lxo)
            invs[lxo] = invb[(ly0 + nh) * 48 + lxo * 16 + l15];

        #pragma unroll
        for (int mt = 0; mt < 2; ++mt)
            #pragma unroll
            for (int r = 0; r < 4; ++r) {
                int q = (py0 + 2 * mh + mt) * 96 + px0 + quad * 4 + r;
                u16* prow = Pb + (size_t)q * 2304 + (ly0 + nh) * 48 + l15;
                float s = 0.f;
                #pragma unroll
                for (int lxo = 0; lxo < 3; ++lxo) {
                    float p = __expf(sf[mt * 3 + lxo][r] * invs[lxo]);
                    u16 h = f2bf(p);
                    prow[lxo * 16] = h;
                    s += bf2f(h);      // l exactly as kpv's MFMA sees P
                }
                lacc[mt][r] += s;
            }
    }

    #pragma unroll
    for (int mt = 0; mt < 2; ++mt)
        #pragma unroll
        for (int r = 0; r < 4; ++r) {
            float v = lacc[mt][r];
            v += __shfl_xor(v, 1);
            v += __shfl_xor(v, 2);
            v += __shfl_xor(v, 4);
            v += __shfl_xor(v, 8);
            if (l15 == 0)
                atomicAdd(&lb[(py0 + 2 * mh + mt) * 96 + px0 + quad * 4 + r], v);
        }
}

// ------------------------------------------------------------- PV GEMM
// grid = nb*288 (XCD-affine). BM=32 q, 4 waves; wave w owns all 32 M-rows x
// its 144 V-cols. ZERO LDS, ZERO barriers: P A-frags and V B-frags straight
// from global (16 B/lane granules; vtp L2-affine per XCD). Epilogue writes
// Z f32 OVERLAYING the first 2304 B of this block's own P rows (each block
// reads its rows fully before writing -> race-free).
__launch_bounds__(256, 2)
__global__ void kpv(u16* __restrict__ P, const u16* __restrict__ vtp,
                    const float* __restrict__ lsum, int b0, int nb) {
    int tid = threadIdx.x;
    int w = tid >> 6, lane = tid & 63, l15 = lane & 15, quad = lane >> 4;
    int bi = blockIdx.x, brel, qt;
    if (nb == 2) { brel = (bi & 7) >> 2; qt = (bi >> 3) * 4 + (bi & 3); }
    else         { brel = 0; qt = bi; }
    int b = b0 + brel;
    int q0 = qt * 32;

    u16* Pb = P + (size_t)brel * 9216 * 2304;
    const u16* Pq = Pb + (size_t)q0 * 2304;
    const u16* vw = vtp + (size_t)b * 576 * 2304 + (size_t)(w * 144 + l15) * 2304 + quad * 8;

    f32x4 acc[18];
    #pragma unroll
    for (int i = 0; i < 18; i++) acc[i] = (f32x4)0.f;

    for (int it = 0; it < 24; ++it) {
        int ko = it * 96;
        short8 pa[2][3];
        #pragma unroll
        for (int mt = 0; mt < 2; ++mt)
            #pragma unroll
            for (int ks = 0; ks < 3; ++ks)
                pa[mt][ks] = *(const short8*)(Pq + (size_t)(mt * 16 + l15) * 2304 + ko + ks * 32 + quad * 8);
        #pragma unroll
        for (int ks = 0; ks < 3; ++ks)
            #pragma unroll
            for (int nt = 0; nt < 9; ++nt) {
                short8 vv = *(const short8*)(vw + (size_t)nt * 16 * 2304 + ko + ks * 32);
                #pragma unroll
                for (int mt = 0; mt < 2; ++mt)
                    acc[mt * 9 + nt] = __builtin_amdgcn_mfma_f32_16x16x32_bf16(
                        pa[mt][ks], vv, acc[mt * 9 + nt], 0, 0, 0);
            }
    }

    // epilogue: Z = acc/(6l), overlay into own P rows (f32, first 2304 B/row)
    const float* lb = lsum + brel * 9216 + q0;
    #pragma unroll
    for (int mt = 0; mt < 2; ++mt)
        #pragma unroll
        for (int r = 0; r < 4; ++r) {
            int row = mt * 16 + quad * 4 + r;
            float rl = 1.0f / (lb[row] * 6.0f);
            float* zr = (float*)(Pb + (size_t)(q0 + row) * 2304) + w * 144;
            #pragma unroll
            for (int nt = 0; nt < 9; ++nt)
                zr[nt * 16 + l15] = acc[mt * 9 + nt][r] * rl;
        }
}

// ------------------------------------------------------------- gather (Z -> out)
// Z lives overlaid in P: row q at byte offset q*4608, 576 f32 (stride 1152 f32).
__global__ void kgather(const u16* __restrict__ P, float* __restrict__ out, int b0) {
    __shared__ float zb[2 * 9 * 580];   // 41760 B
    int bi = blockIdx.x;                // nb*96*12
    int brel = bi / (96 * 12);
    int rem = bi % (96 * 12);
    int b = b0 + brel;
    int q = rem / 12, xt = rem % 12;
    int ox0 = xt * 16, p0 = ox0 >> 1;
    const float* Zb = (const float*)(P + (size_t)brel * 9216 * 2304);
    int tid = threadIdx.x;
    for (int id = tid; id < 2592; id += 256) {
        int pi = id / 1296, r2 = id % 1296;
        int pxi = r2 / 144, n4 = r2 % 144;
        int py = q + pi; if (py > 95) py = 95;
        int px = p0 + pxi; if (px > 95) px = 95;
        *(float4*)&zb[(pi * 9 + pxi) * 580 + n4 * 4] =
            *(const float4*)&Zb[(size_t)(py * 96 + px) * 1152 + n4 * 4];
    }
    __syncthreads();
    int xi = tid & 15, cq = tid >> 4;
    int ox = ox0 + xi;
    bool oxv = ox <= 190;
    int ntx, txl[2], pxl[2];
    if (xi & 1) { ntx = 2; txl[0] = 0; pxl[0] = (xi + 1) >> 1; txl[1] = 2; pxl[1] = (xi - 1) >> 1; }
    else        { ntx = 1; txl[0] = 1; pxl[0] = xi >> 1; txl[1] = 1; pxl[1] = xi >> 1; }
    int oy0 = 2 * q;
    #pragma unroll
    for (int ck = 0; ck < 4; ++ck) {
        int c = cq + ck * 16;
        float v0 = 0.f, v1 = 0.f;
        for (int j = 0; j < ntx; ++j) {
            int tx = txl[j], pxi = pxl[j];
            v0 += zb[(0 * 9 + pxi) * 580 + (3 + tx) * 64 + c];
            v1 += zb[(1 * 9 + pxi) * 580 + (0 + tx) * 64 + c];
            v1 += zb[(0 * 9 + pxi) * 580 + (6 + tx) * 64 + c];
        }
        if (oxv) {
            float* o = out + (((size_t)(b * 64 + c) * 191 + oy0) * 191 + ox);
            *o = v0;
            if (q < 95) *(o + 191) = v1;
        }
    }
}

// --------------------------------------------------------------------- host
extern "C" void kernel_launch(void* const* d_in, const int* in_sizes, int n_in,
                              void* d_out, int out_size, void* d_ws, size_t ws_size,
                              hipStream_t stream) {
    const float* input = (const float*)d_in[0];
    const float* small = (const float*)d_in[1];
    const float* w1 = (const float*)d_in[2];
    const float* b1 = (const float*)d_in[3];
    const float* a1 = (const float*)d_in[4];
    const float* w2 = (const float*)d_in[5];
    const float* b2 = (const float*)d_in[6];
    const float* a2 = (const float*)d_in[7];
    const float* wa = (const float*)d_in[8];
    const float* ba = (const float*)d_in[9];
    const float* aa = (const float*)d_in[10];

    char* ws = (char*)d_ws;
    u16* xf16 = (u16*)(ws + 0);             //  2,458,624
    u16* rkl = (u16*)(ws + 2458624);        //    640,000
    float* ef = (float*)(ws + 3098624);     //  2,560,000
    u16* vtp = (u16*)(ws + 5658624);        // 10,616,832
    float* invn = (float*)(ws + 16275456);  //     36,864
    const size_t PREP = 16312320;
    float* out = (float*)d_out;

    // nb=2: lsum 73,728 + P 84,934,656 -> total 101,320,704 (proven <= ws)
    int nb = (ws_size >= (size_t)101320704) ? 2 : 1;
    float* lsum = (float*)(ws + PREP);
    u16* P = (u16*)(ws + PREP + (size_t)nb * 36864);

    kzero<<<1024, 256, 0, stream>>>((float4*)ws, 5658624 / 16);   // halo'd arrays
    kmatch<<<384, 256, 0, stream>>>(input, w1, b1, a1, xf16);
    ksmall<<<192, 256, 0, stream>>>(small, wa, ba, aa, w2, b2, a2, ef, rkl);
    kinvnorm<<<36, 256, 0, stream>>>(rkl, invn);
    kvtp<<<2304, 256, 0, stream>>>(ef, vtp);

    for (int b0 = 0; b0 < 4; b0 += nb) {
        kzero<<<36, 256, 0, stream>>>((float4*)lsum, (long)nb * 2304);
        kscoreP<<<nb * 576, 256, 0, stream>>>(xf16, rkl, invn, P, lsum, b0, nb);
        kpv<<<nb * 288, 256, 0, stream>>>(P, vtp, lsum, b0, nb);
        kgather<<<nb * 1152, 256, 0, stream>>>(P, out, b0);
    }
}